// Round 2
// baseline (279.161 us; speedup 1.0000x reference)
//
#include <hip/hip_runtime.h>
#include <stdint.h>

#define B_  2
#define S_  2048
#define D_  1024
#define H_  16
#define HD_ 64
#define TOK (B_*S_)   // 4096

typedef __bf16 bf16x8 __attribute__((ext_vector_type(8)));
typedef float  f32x4  __attribute__((ext_vector_type(4)));

static_assert(sizeof(bf16x8) == 16, "bf16x8 must be 16B");

__device__ __forceinline__ unsigned short f2bf(float f) {
    unsigned int u = __builtin_bit_cast(unsigned int, f);
    u += 0x7FFFu + ((u >> 16) & 1u);   // RNE; inputs are finite
    return (unsigned short)(u >> 16);
}

__device__ __forceinline__ float fexp2(float x) { return __builtin_amdgcn_exp2f(x); }

__device__ __forceinline__ f32x4 mfma16(bf16x8 a, bf16x8 b, f32x4 c) {
    return __builtin_amdgcn_mfma_f32_16x16x32_bf16(a, b, c, 0, 0, 0);
}

// ---------------------------------------------------------------------------
// K0: Wo [1024(in)][1024(out)] fp32  ->  WoT [out][in] bf16
// grid (16,16), block 256
// ---------------------------------------------------------------------------
__global__ __launch_bounds__(256) void k_transpose_wo(
    const float* __restrict__ Wo, unsigned short* __restrict__ WoT)
{
    __shared__ float t[64][65];
    const int i0 = blockIdx.x * 64;   // in-dim tile
    const int o0 = blockIdx.y * 64;   // out-dim tile
    const int tid = threadIdx.x;
    #pragma unroll
    for (int p = 0; p < 16; ++p) {
        int idx = tid + p * 256;
        int r = idx >> 6, c = idx & 63;
        t[r][c] = Wo[(size_t)(i0 + r) * D_ + o0 + c];
    }
    __syncthreads();
    #pragma unroll
    for (int p = 0; p < 16; ++p) {
        int idx = tid + p * 256;
        int r = idx >> 6, c = idx & 63;   // r: out-row in tile, c: in-col in tile
        WoT[(size_t)(o0 + r) * D_ + i0 + c] = f2bf(t[c][r]);
    }
}

// ---------------------------------------------------------------------------
// K1: per-head QKV projection.
//   Q -> [B,H,S,HD] bf16, scaled by log2(e)/8 (folds softmax scale + exp2)
//   K -> [B,H,S,HD] bf16
//   V -> transposed [B,H,HD,S] bf16 (so PV A-fragments are contiguous)
// grid (TOK/64, H, 3), block 256. Each thread: 4 tokens x 4 outputs.
// ---------------------------------------------------------------------------
__global__ __launch_bounds__(256) void k_qkv(
    const float* __restrict__ X,
    const float* __restrict__ Wq, const float* __restrict__ bq,
    const float* __restrict__ Wk, const float* __restrict__ bk,
    const float* __restrict__ Wv, const float* __restrict__ bv,
    unsigned short* __restrict__ Qo, unsigned short* __restrict__ Ko,
    unsigned short* __restrict__ Vt)
{
    __shared__ float Xs[64][65];   // padded: conflict-free column reads
    __shared__ float Ws[64][64];
    __shared__ float bs[64];

    const int t0 = blockIdx.x * 64;
    const int h  = blockIdx.y;
    const int z  = blockIdx.z;                       // 0=Q 1=K 2=V
    const float* W  = (z == 0) ? Wq : (z == 1) ? Wk : Wv;
    const float* bb = (z == 0) ? bq : (z == 1) ? bk : bv;
    const int tid = threadIdx.x;

    #pragma unroll
    for (int p = 0; p < 16; ++p) {
        int idx = tid + p * 256;
        int r = idx >> 6, c = idx & 63;
        Xs[r][c] = X[(size_t)(t0 + r) * D_ + h * HD_ + c];
        Ws[r][c] = W[h * HD_ * HD_ + idx];
    }
    if (tid < 64) bs[tid] = bb[h * HD_ + tid];
    __syncthreads();

    const int tq = tid & 15;           // token sub-index (tokens tq + 16a)
    const int eb = (tid >> 4) * 4;     // output base (0..60)
    float acc[4][4];
    #pragma unroll
    for (int a = 0; a < 4; ++a)
        #pragma unroll
        for (int e = 0; e < 4; ++e) acc[a][e] = bs[eb + e];

    #pragma unroll 4
    for (int d = 0; d < 64; ++d) {
        float w0 = Ws[d][eb + 0], w1 = Ws[d][eb + 1];
        float w2 = Ws[d][eb + 2], w3 = Ws[d][eb + 3];
        #pragma unroll
        for (int a = 0; a < 4; ++a) {
            float xv = Xs[tq + 16 * a][d];
            acc[a][0] += xv * w0; acc[a][1] += xv * w1;
            acc[a][2] += xv * w2; acc[a][3] += xv * w3;
        }
    }

    const float scq = 0.18033688011112042f;  // log2(e)/8
    #pragma unroll
    for (int a = 0; a < 4; ++a) {
        int tok = t0 + tq + 16 * a;
        int b = tok >> 11, s = tok & (S_ - 1);
        if (z == 2) {
            size_t base = ((size_t)(b * H_ + h) * HD_ + eb) * S_ + s;
            #pragma unroll
            for (int e = 0; e < 4; ++e)
                Vt[base + (size_t)e * S_] = f2bf(acc[a][e]);
        } else {
            float sc = (z == 0) ? scq : 1.0f;
            unsigned int lo = f2bf(acc[a][0] * sc) | ((unsigned int)f2bf(acc[a][1] * sc) << 16);
            unsigned int hi = f2bf(acc[a][2] * sc) | ((unsigned int)f2bf(acc[a][3] * sc) << 16);
            unsigned short* dst = (z == 0) ? Qo : Ko;
            size_t idx = ((size_t)(b * H_ + h) * S_ + s) * HD_ + eb;
            *reinterpret_cast<uint2*>(&dst[idx]) = make_uint2(lo, hi);
        }
    }
}

// ---------------------------------------------------------------------------
// K2: flash attention. Swapped QK^T: S^T = mfma(K, Q) so each lane owns one
// q-column; online softmax m/l are per-lane scalars, reduce = 2x shfl_xor.
// Block = 4 waves x 16 q-rows = 64 q-rows; 32 keys/iter; K,V staged in LDS.
// grid (S/64, B*H), block 256.
// ---------------------------------------------------------------------------
__global__ __launch_bounds__(256) void k_attn(
    const unsigned short* __restrict__ Q,
    const unsigned short* __restrict__ K,
    const unsigned short* __restrict__ V,
    unsigned short* __restrict__ O)
{
    __shared__ unsigned short K_lds[32 * 72];     // 32 keys x (64 dims + 8 pad)
    __shared__ unsigned short V_lds[64 * 40];     // 64 dims x (32 keys + 8 pad)
    __shared__ unsigned short P_lds[4][16 * 40];  // per-wave: 16 q x (32 keys + 8 pad)

    const int bh = blockIdx.y;
    const unsigned short* Qp = Q + (size_t)bh * S_ * HD_;
    const unsigned short* Kp = K + (size_t)bh * S_ * HD_;
    const unsigned short* Vp = V + (size_t)bh * HD_ * S_;

    const int tid  = threadIdx.x;
    const int lane = tid & 63, w = tid >> 6;
    const int g = lane >> 4, q = lane & 15;
    const int q0 = blockIdx.x * 64 + w * 16;

    // Q B-fragments (B[k][n]=Q[q][dim], contiguous 16B per lane)
    bf16x8 qf0 = *reinterpret_cast<const bf16x8*>(&Qp[(size_t)(q0 + q) * HD_ + 8 * g]);
    bf16x8 qf1 = *reinterpret_cast<const bf16x8*>(&Qp[(size_t)(q0 + q) * HD_ + 32 + 8 * g]);

    f32x4 acc0 = {0.f, 0.f, 0.f, 0.f}, acc1 = acc0, acc2 = acc0, acc3 = acc0;
    float m = -3.0e38f, l = 0.0f;

    const int kr = tid >> 3, ks = (tid & 7) * 8;  // K staging: 32 rows x 8 segs
    const int vr = tid >> 2, vs = (tid & 3) * 8;  // V staging: 64 rows x 4 segs
    unsigned short* Pw = P_lds[w];

    for (int kv = 0; kv < S_; kv += 32) {
        // ---- stage K (32x64) and V^T (64x32) tiles into padded LDS ----
        *reinterpret_cast<uint4*>(&K_lds[kr * 72 + ks]) =
            *reinterpret_cast<const uint4*>(&Kp[(size_t)(kv + kr) * HD_ + ks]);
        *reinterpret_cast<uint4*>(&V_lds[vr * 40 + vs]) =
            *reinterpret_cast<const uint4*>(&Vp[(size_t)vr * S_ + kv + vs]);
        __syncthreads();

        // ---- fragment reads (K now, V for use after 2nd barrier) ----
        bf16x8 k00 = *reinterpret_cast<const bf16x8*>(&K_lds[q * 72 + 8 * g]);
        bf16x8 k01 = *reinterpret_cast<const bf16x8*>(&K_lds[q * 72 + 32 + 8 * g]);
        bf16x8 k10 = *reinterpret_cast<const bf16x8*>(&K_lds[(16 + q) * 72 + 8 * g]);
        bf16x8 k11 = *reinterpret_cast<const bf16x8*>(&K_lds[(16 + q) * 72 + 32 + 8 * g]);
        bf16x8 vf0 = *reinterpret_cast<const bf16x8*>(&V_lds[(0 * 16 + q) * 40 + 8 * g]);
        bf16x8 vf1 = *reinterpret_cast<const bf16x8*>(&V_lds[(1 * 16 + q) * 40 + 8 * g]);
        bf16x8 vf2 = *reinterpret_cast<const bf16x8*>(&V_lds[(2 * 16 + q) * 40 + 8 * g]);
        bf16x8 vf3 = *reinterpret_cast<const bf16x8*>(&V_lds[(3 * 16 + q) * 40 + 8 * g]);

        // ---- S^T = K . Q^T : lane holds keys {t*16+4g+j} for column q ----
        f32x4 z4 = {0.f, 0.f, 0.f, 0.f};
        f32x4 s0 = mfma16(k00, qf0, z4); s0 = mfma16(k01, qf1, s0);
        f32x4 s1 = mfma16(k10, qf0, z4); s1 = mfma16(k11, qf1, s1);

        // ---- online softmax (base-2; scale folded into Q) ----
        float pm = fmaxf(fmaxf(fmaxf(s0[0], s0[1]), fmaxf(s0[2], s0[3])),
                         fmaxf(fmaxf(s1[0], s1[1]), fmaxf(s1[2], s1[3])));
        pm = fmaxf(pm, __shfl_xor(pm, 16));
        pm = fmaxf(pm, __shfl_xor(pm, 32));
        float mn  = fmaxf(m, pm);
        float scl = fexp2(m - mn);
        m = mn;
        float p0 = fexp2(s0[0] - mn), p1 = fexp2(s0[1] - mn);
        float p2 = fexp2(s0[2] - mn), p3 = fexp2(s0[3] - mn);
        float p4 = fexp2(s1[0] - mn), p5 = fexp2(s1[1] - mn);
        float p6 = fexp2(s1[2] - mn), p7 = fexp2(s1[3] - mn);
        float ps = ((p0 + p1) + (p2 + p3)) + ((p4 + p5) + (p6 + p7));
        ps += __shfl_xor(ps, 16);
        ps += __shfl_xor(ps, 32);
        l = l * scl + ps;
        acc0 *= scl; acc1 *= scl; acc2 *= scl; acc3 *= scl;

        // ---- P -> LDS (row q, cols = keys), packed bf16 b64 writes ----
        unsigned int a0 = f2bf(p0) | ((unsigned int)f2bf(p1) << 16);
        unsigned int a1 = f2bf(p2) | ((unsigned int)f2bf(p3) << 16);
        unsigned int b0 = f2bf(p4) | ((unsigned int)f2bf(p5) << 16);
        unsigned int b1 = f2bf(p6) | ((unsigned int)f2bf(p7) << 16);
        *reinterpret_cast<uint2*>(&Pw[q * 40 + 4 * g])      = make_uint2(a0, a1);
        *reinterpret_cast<uint2*>(&Pw[q * 40 + 16 + 4 * g]) = make_uint2(b0, b1);
        __syncthreads();   // P visible cross-lane; K/V reads done before restage

        // ---- O^T += V^T . P^T ----
        bf16x8 pf = *reinterpret_cast<const bf16x8*>(&Pw[q * 40 + 8 * g]);
        acc0 = mfma16(vf0, pf, acc0);
        acc1 = mfma16(vf1, pf, acc1);
        acc2 = mfma16(vf2, pf, acc2);
        acc3 = mfma16(vf3, pf, acc3);
    }

    // ---- epilogue: O[b, s=q0+q, h*64 + d] = acc/l ----
    const float inv = 1.0f / l;
    const int b = bh >> 4, h = bh & 15;
    size_t row = (size_t)(b * S_ + q0 + q) * D_ + h * HD_ + 4 * g;
    {
        unsigned int lo, hi;
        lo = f2bf(acc0[0]*inv) | ((unsigned int)f2bf(acc0[1]*inv) << 16);
        hi = f2bf(acc0[2]*inv) | ((unsigned int)f2bf(acc0[3]*inv) << 16);
        *reinterpret_cast<uint2*>(&O[row + 0])  = make_uint2(lo, hi);
        lo = f2bf(acc1[0]*inv) | ((unsigned int)f2bf(acc1[1]*inv) << 16);
        hi = f2bf(acc1[2]*inv) | ((unsigned int)f2bf(acc1[3]*inv) << 16);
        *reinterpret_cast<uint2*>(&O[row + 16]) = make_uint2(lo, hi);
        lo = f2bf(acc2[0]*inv) | ((unsigned int)f2bf(acc2[1]*inv) << 16);
        hi = f2bf(acc2[2]*inv) | ((unsigned int)f2bf(acc2[3]*inv) << 16);
        *reinterpret_cast<uint2*>(&O[row + 32]) = make_uint2(lo, hi);
        lo = f2bf(acc3[0]*inv) | ((unsigned int)f2bf(acc3[1]*inv) << 16);
        hi = f2bf(acc3[2]*inv) | ((unsigned int)f2bf(acc3[3]*inv) << 16);
        *reinterpret_cast<uint2*>(&O[row + 48]) = make_uint2(lo, hi);
    }
}

// ---------------------------------------------------------------------------
// K3: out = O_attn(bf16) @ Wo + bo, fp32 out. A row-major, B from WoT [n][k].
// Block = 4 waves; wave = 16 m-rows x 64 n-cols. grid (TOK/64, D/64).
// ---------------------------------------------------------------------------
__global__ __launch_bounds__(256) void k_out(
    const unsigned short* __restrict__ A,
    const unsigned short* __restrict__ Wt,
    const float* __restrict__ bo,
    float* __restrict__ C)
{
    const int tid  = threadIdx.x;
    const int lane = tid & 63, w = tid >> 6;
    const int g = lane >> 4, q = lane & 15;
    const int m0 = blockIdx.x * 64 + w * 16;
    const int n0 = blockIdx.y * 64;

    f32x4 c0 = {0.f, 0.f, 0.f, 0.f}, c1 = c0, c2 = c0, c3 = c0;
    #pragma unroll 4
    for (int kk = 0; kk < D_; kk += 32) {
        bf16x8 af  = *reinterpret_cast<const bf16x8*>(&A [(size_t)(m0 + q) * D_ + kk + 8 * g]);
        bf16x8 bf0 = *reinterpret_cast<const bf16x8*>(&Wt[(size_t)(n0 + q) * D_ + kk + 8 * g]);
        bf16x8 bf1 = *reinterpret_cast<const bf16x8*>(&Wt[(size_t)(n0 + 16 + q) * D_ + kk + 8 * g]);
        bf16x8 bf2 = *reinterpret_cast<const bf16x8*>(&Wt[(size_t)(n0 + 32 + q) * D_ + kk + 8 * g]);
        bf16x8 bf3 = *reinterpret_cast<const bf16x8*>(&Wt[(size_t)(n0 + 48 + q) * D_ + kk + 8 * g]);
        c0 = mfma16(af, bf0, c0);
        c1 = mfma16(af, bf1, c1);
        c2 = mfma16(af, bf2, c2);
        c3 = mfma16(af, bf3, c3);
    }
    float bia0 = bo[n0 + q],      bia1 = bo[n0 + 16 + q];
    float bia2 = bo[n0 + 32 + q], bia3 = bo[n0 + 48 + q];
    #pragma unroll
    for (int j = 0; j < 4; ++j) {
        size_t r = (size_t)(m0 + 4 * g + j) * D_;
        C[r + n0 + q]      = c0[j] + bia0;
        C[r + n0 + 16 + q] = c1[j] + bia1;
        C[r + n0 + 32 + q] = c2[j] + bia2;
        C[r + n0 + 48 + q] = c3[j] + bia3;
    }
}

// ---------------------------------------------------------------------------
extern "C" void kernel_launch(void* const* d_in, const int* in_sizes, int n_in,
                              void* d_out, int out_size, void* d_ws, size_t ws_size,
                              hipStream_t stream)
{
    const float* X  = (const float*)d_in[0];
    const float* Wq = (const float*)d_in[1];
    const float* bq = (const float*)d_in[2];
    const float* Wk = (const float*)d_in[3];
    const float* bk = (const float*)d_in[4];
    const float* Wv = (const float*)d_in[5];
    const float* bv = (const float*)d_in[6];
    const float* Wo = (const float*)d_in[7];
    const float* bo = (const float*)d_in[8];
    float* out = (float*)d_out;

    unsigned short* ws = (unsigned short*)d_ws;
    const size_t QN = (size_t)B_ * H_ * S_ * HD_;   // 4M elements
    unsigned short* Qb  = ws;             // 8 MB
    unsigned short* Kb  = ws + QN;        // 8 MB
    unsigned short* Vtb = ws + 2 * QN;    // 8 MB (transposed V)
    unsigned short* Ob  = ws + 3 * QN;    // 8 MB (attention output, bf16)
    unsigned short* WoT = ws + 4 * QN;    // 2 MB (Wo^T bf16)

    k_transpose_wo<<<dim3(16, 16), 256, 0, stream>>>(Wo, WoT);
    k_qkv<<<dim3(TOK / 64, H_, 3), 256, 0, stream>>>(X, Wq, bq, Wk, bk, Wv, bv, Qb, Kb, Vtb);
    k_attn<<<dim3(S_ / 64, B_ * H_), 256, 0, stream>>>(Qb, Kb, Vtb, Ob);
    k_out<<<dim3(TOK / 64, D_ / 64), 256, 0, stream>>>(Ob, WoT, bo, out);
}

// Round 3
// 251.725 us; speedup vs baseline: 1.1090x; 1.1090x over previous
//
#include <hip/hip_runtime.h>
#include <stdint.h>

#define B_  2
#define S_  2048
#define D_  1024
#define H_  16
#define HD_ 64
#define TOK (B_*S_)   // 4096

typedef __bf16 bf16x8 __attribute__((ext_vector_type(8)));
typedef __bf16 bf16x4 __attribute__((ext_vector_type(4)));
typedef float  f32x4  __attribute__((ext_vector_type(4)));

static_assert(sizeof(bf16x8) == 16, "bf16x8 must be 16B");
static_assert(sizeof(bf16x4) == 8,  "bf16x4 must be 8B");

__device__ __forceinline__ float fexp2(float x) { return __builtin_amdgcn_exp2f(x); }

__device__ __forceinline__ f32x4 mfma16(bf16x8 a, bf16x8 b, f32x4 c) {
    return __builtin_amdgcn_mfma_f32_16x16x32_bf16(a, b, c, 0, 0, 0);
}

// ---------------------------------------------------------------------------
// K0: Wo [1024(in)][1024(out)] fp32  ->  WoT [out][in] bf16
// grid (16,16), block 256
// ---------------------------------------------------------------------------
__global__ __launch_bounds__(256) void k_transpose_wo(
    const float* __restrict__ Wo, unsigned short* __restrict__ WoT)
{
    __shared__ float t[64][65];
    const int i0 = blockIdx.x * 64;   // in-dim tile
    const int o0 = blockIdx.y * 64;   // out-dim tile
    const int tid = threadIdx.x;
    #pragma unroll
    for (int p = 0; p < 16; ++p) {
        int idx = tid + p * 256;
        int r = idx >> 6, c = idx & 63;
        t[r][c] = Wo[(size_t)(i0 + r) * D_ + o0 + c];
    }
    __syncthreads();
    #pragma unroll
    for (int p = 0; p < 16; ++p) {
        int idx = tid + p * 256;
        int r = idx >> 6, c = idx & 63;   // r: out-row in tile, c: in-col in tile
        reinterpret_cast<__bf16*>(WoT)[(size_t)(o0 + r) * D_ + i0 + c] = (__bf16)t[c][r];
    }
}

// ---------------------------------------------------------------------------
// K1: per-head QKV projection.
//   Q -> [B,H,S,HD] bf16, scaled by log2(e)/8 (folds softmax scale + exp2)
//   K -> [B,H,S,HD] bf16
//   V -> transposed [B,H,HD,S] bf16 (so PV A-fragments are contiguous)
// grid (TOK/64, H, 3), block 256. Each thread: 4 tokens x 4 outputs.
// ---------------------------------------------------------------------------
__global__ __launch_bounds__(256) void k_qkv(
    const float* __restrict__ X,
    const float* __restrict__ Wq, const float* __restrict__ bq,
    const float* __restrict__ Wk, const float* __restrict__ bk,
    const float* __restrict__ Wv, const float* __restrict__ bv,
    unsigned short* __restrict__ Qo, unsigned short* __restrict__ Ko,
    unsigned short* __restrict__ Vt)
{
    __shared__ float Xs[64][65];   // padded: conflict-free column reads
    __shared__ float Ws[64][64];
    __shared__ float bs[64];

    const int t0 = blockIdx.x * 64;
    const int h  = blockIdx.y;
    const int z  = blockIdx.z;                       // 0=Q 1=K 2=V
    const float* W  = (z == 0) ? Wq : (z == 1) ? Wk : Wv;
    const float* bb = (z == 0) ? bq : (z == 1) ? bk : bv;
    const int tid = threadIdx.x;

    #pragma unroll
    for (int p = 0; p < 16; ++p) {
        int idx = tid + p * 256;
        int r = idx >> 6, c = idx & 63;
        Xs[r][c] = X[(size_t)(t0 + r) * D_ + h * HD_ + c];
        Ws[r][c] = W[h * HD_ * HD_ + idx];
    }
    if (tid < 64) bs[tid] = bb[h * HD_ + tid];
    __syncthreads();

    const int tq = tid & 15;           // token sub-index (tokens tq + 16a)
    const int eb = (tid >> 4) * 4;     // output base (0..60)
    float acc[4][4];
    #pragma unroll
    for (int a = 0; a < 4; ++a)
        #pragma unroll
        for (int e = 0; e < 4; ++e) acc[a][e] = bs[eb + e];

    #pragma unroll 4
    for (int d = 0; d < 64; ++d) {
        float w0 = Ws[d][eb + 0], w1 = Ws[d][eb + 1];
        float w2 = Ws[d][eb + 2], w3 = Ws[d][eb + 3];
        #pragma unroll
        for (int a = 0; a < 4; ++a) {
            float xv = Xs[tq + 16 * a][d];
            acc[a][0] += xv * w0; acc[a][1] += xv * w1;
            acc[a][2] += xv * w2; acc[a][3] += xv * w3;
        }
    }

    const float scq = 0.18033688011112042f;  // log2(e)/8
    #pragma unroll
    for (int a = 0; a < 4; ++a) {
        int tok = t0 + tq + 16 * a;
        int b = tok >> 11, s = tok & (S_ - 1);
        if (z == 2) {
            size_t base = ((size_t)(b * H_ + h) * HD_ + eb) * S_ + s;
            #pragma unroll
            for (int e = 0; e < 4; ++e)
                reinterpret_cast<__bf16*>(Vt)[base + (size_t)e * S_] = (__bf16)acc[a][e];
        } else {
            float sc = (z == 0) ? scq : 1.0f;
            bf16x4 ov = { (__bf16)(acc[a][0] * sc), (__bf16)(acc[a][1] * sc),
                          (__bf16)(acc[a][2] * sc), (__bf16)(acc[a][3] * sc) };
            unsigned short* dst = (z == 0) ? Qo : Ko;
            size_t idx = ((size_t)(b * H_ + h) * S_ + s) * HD_ + eb;
            *reinterpret_cast<bf16x4*>(&dst[idx]) = ov;
        }
    }
}

// ---------------------------------------------------------------------------
// K2: flash attention, v2.
//  - Swapped QK^T: S^T = mfma(K, Q); lane owns one q-column.
//  - Double-buffered K/V LDS, async-stage split (T14): 1 barrier/iter.
//  - Defer-max (T13, THR=8 log2-domain): fast path skips shuffles + rescale.
//  - Per-lane partial l, reduced once in epilogue.
// Block = 4 waves x 16 q-rows; 32 keys/iter. grid (S/64, B*H), block 256.
// ---------------------------------------------------------------------------
__global__ __launch_bounds__(256) void k_attn(
    const unsigned short* __restrict__ Q,
    const unsigned short* __restrict__ K,
    const unsigned short* __restrict__ V,
    unsigned short* __restrict__ O)
{
    __shared__ unsigned short K_lds[2][32 * 72];  // 32 keys x (64 dims + 8 pad)
    __shared__ unsigned short V_lds[2][64 * 40];  // 64 dims x (32 keys + 8 pad)
    __shared__ unsigned short P_lds[4][16 * 40];  // per-wave: 16 q x (32 keys + 8 pad)

    const int bh = blockIdx.y;
    const unsigned short* Qp = Q + (size_t)bh * S_ * HD_;
    const unsigned short* Kp = K + (size_t)bh * S_ * HD_;
    const unsigned short* Vp = V + (size_t)bh * HD_ * S_;

    const int tid  = threadIdx.x;
    const int lane = tid & 63, w = tid >> 6;
    const int g = lane >> 4, q = lane & 15;
    const int q0 = blockIdx.x * 64 + w * 16;

    // Q B-fragments (B[k][n]=Q[q][dim], contiguous 16B per lane)
    bf16x8 qf0 = *reinterpret_cast<const bf16x8*>(&Qp[(size_t)(q0 + q) * HD_ + 8 * g]);
    bf16x8 qf1 = *reinterpret_cast<const bf16x8*>(&Qp[(size_t)(q0 + q) * HD_ + 32 + 8 * g]);

    f32x4 acc0 = {0.f, 0.f, 0.f, 0.f}, acc1 = acc0, acc2 = acc0, acc3 = acc0;
    float m = -3.0e38f, lp = 0.0f;

    const int kr = tid >> 3, ks = (tid & 7) * 8;  // K staging: 32 rows x 8 segs
    const int vr = tid >> 2, vs = (tid & 3) * 8;  // V staging: 64 rows x 4 segs
    unsigned short* Pw = P_lds[w];

    const unsigned short* kSrc = Kp + (size_t)kr * HD_ + ks;  // += 32*HD_ per tile
    const unsigned short* vSrc = Vp + (size_t)vr * S_  + vs;  // += 32 per tile

    // ---- prologue: stage tile 0 ----
    {
        uint4 k0 = *reinterpret_cast<const uint4*>(kSrc);
        uint4 v0 = *reinterpret_cast<const uint4*>(vSrc);
        *reinterpret_cast<uint4*>(&K_lds[0][kr * 72 + ks]) = k0;
        *reinterpret_cast<uint4*>(&V_lds[0][vr * 40 + vs]) = v0;
    }
    __syncthreads();

    const int NT = S_ / 32;   // 64 tiles
    for (int t = 0; t < NT; ++t) {
        const int cur = t & 1, nxt = cur ^ 1;

        // ---- issue next tile's global loads early (latency hides under compute) ----
        uint4 kn, vn;
        const bool more = (t + 1 < NT);
        if (more) {
            kn = *reinterpret_cast<const uint4*>(kSrc + (size_t)(t + 1) * 32 * HD_);
            vn = *reinterpret_cast<const uint4*>(vSrc + (size_t)(t + 1) * 32);
        }

        // ---- fragment reads from buf[cur] ----
        const unsigned short* Kb = K_lds[cur];
        const unsigned short* Vb = V_lds[cur];
        bf16x8 k00 = *reinterpret_cast<const bf16x8*>(&Kb[q * 72 + 8 * g]);
        bf16x8 k01 = *reinterpret_cast<const bf16x8*>(&Kb[q * 72 + 32 + 8 * g]);
        bf16x8 k10 = *reinterpret_cast<const bf16x8*>(&Kb[(16 + q) * 72 + 8 * g]);
        bf16x8 k11 = *reinterpret_cast<const bf16x8*>(&Kb[(16 + q) * 72 + 32 + 8 * g]);
        bf16x8 vf0 = *reinterpret_cast<const bf16x8*>(&Vb[(0 * 16 + q) * 40 + 8 * g]);
        bf16x8 vf1 = *reinterpret_cast<const bf16x8*>(&Vb[(1 * 16 + q) * 40 + 8 * g]);
        bf16x8 vf2 = *reinterpret_cast<const bf16x8*>(&Vb[(2 * 16 + q) * 40 + 8 * g]);
        bf16x8 vf3 = *reinterpret_cast<const bf16x8*>(&Vb[(3 * 16 + q) * 40 + 8 * g]);

        // ---- S^T = K . Q^T : lane holds keys {blk*16 + 4g + j} for column q ----
        f32x4 z4 = {0.f, 0.f, 0.f, 0.f};
        f32x4 s0 = mfma16(k00, qf0, z4); s0 = mfma16(k01, qf1, s0);
        f32x4 s1 = mfma16(k10, qf0, z4); s1 = mfma16(k11, qf1, s1);

        // ---- online softmax, defer-max fast path (T13) ----
        float pmax = fmaxf(fmaxf(fmaxf(s0[0], s0[1]), fmaxf(s0[2], s0[3])),
                           fmaxf(fmaxf(s1[0], s1[1]), fmaxf(s1[2], s1[3])));
        if (!__all(pmax - m <= 8.0f)) {
            float pm = pmax;
            pm = fmaxf(pm, __shfl_xor(pm, 16));
            pm = fmaxf(pm, __shfl_xor(pm, 32));
            float mn  = fmaxf(m, pm);
            float scl = fexp2(m - mn);
            m = mn;
            lp *= scl;
            acc0 *= scl; acc1 *= scl; acc2 *= scl; acc3 *= scl;
        }
        float p0 = fexp2(s0[0] - m), p1 = fexp2(s0[1] - m);
        float p2 = fexp2(s0[2] - m), p3 = fexp2(s0[3] - m);
        float p4 = fexp2(s1[0] - m), p5 = fexp2(s1[1] - m);
        float p6 = fexp2(s1[2] - m), p7 = fexp2(s1[3] - m);
        lp += ((p0 + p1) + (p2 + p3)) + ((p4 + p5) + (p6 + p7));

        // ---- P -> per-wave LDS (row q, cols = keys), native cvt_pk casts ----
        bf16x4 pa = { (__bf16)p0, (__bf16)p1, (__bf16)p2, (__bf16)p3 };
        bf16x4 pb = { (__bf16)p4, (__bf16)p5, (__bf16)p6, (__bf16)p7 };
        *reinterpret_cast<bf16x4*>(&Pw[q * 40 + 4 * g])      = pa;
        *reinterpret_cast<bf16x4*>(&Pw[q * 40 + 16 + 4 * g]) = pb;

        // ---- O^T += V^T . P^T (same-wave LDS: in-order, lgkmcnt by compiler) ----
        bf16x8 pf = *reinterpret_cast<const bf16x8*>(&Pw[q * 40 + 8 * g]);
        acc0 = mfma16(vf0, pf, acc0);
        acc1 = mfma16(vf1, pf, acc1);
        acc2 = mfma16(vf2, pf, acc2);
        acc3 = mfma16(vf3, pf, acc3);

        // ---- write next tile into buf[nxt]; single barrier per iter ----
        if (more) {
            *reinterpret_cast<uint4*>(&K_lds[nxt][kr * 72 + ks]) = kn;
            *reinterpret_cast<uint4*>(&V_lds[nxt][vr * 40 + vs]) = vn;
        }
        __syncthreads();
    }

    // ---- epilogue: reduce l across the 4 lanes of column q, write O ----
    lp += __shfl_xor(lp, 16);
    lp += __shfl_xor(lp, 32);
    const float inv = 1.0f / lp;
    const int b = bh >> 4, h = bh & 15;
    size_t row = (size_t)(b * S_ + q0 + q) * D_ + h * HD_ + 4 * g;
    __bf16* Ob = reinterpret_cast<__bf16*>(O);
    bf16x4 o0 = { (__bf16)(acc0[0]*inv), (__bf16)(acc0[1]*inv),
                  (__bf16)(acc0[2]*inv), (__bf16)(acc0[3]*inv) };
    bf16x4 o1 = { (__bf16)(acc1[0]*inv), (__bf16)(acc1[1]*inv),
                  (__bf16)(acc1[2]*inv), (__bf16)(acc1[3]*inv) };
    bf16x4 o2 = { (__bf16)(acc2[0]*inv), (__bf16)(acc2[1]*inv),
                  (__bf16)(acc2[2]*inv), (__bf16)(acc2[3]*inv) };
    bf16x4 o3 = { (__bf16)(acc3[0]*inv), (__bf16)(acc3[1]*inv),
                  (__bf16)(acc3[2]*inv), (__bf16)(acc3[3]*inv) };
    *reinterpret_cast<bf16x4*>(&Ob[row + 0])  = o0;
    *reinterpret_cast<bf16x4*>(&Ob[row + 16]) = o1;
    *reinterpret_cast<bf16x4*>(&Ob[row + 32]) = o2;
    *reinterpret_cast<bf16x4*>(&Ob[row + 48]) = o3;
}

// ---------------------------------------------------------------------------
// K3: out = O_attn(bf16) @ Wo + bo, fp32 out. A row-major, B from WoT [n][k].
// Block = 4 waves; wave = 16 m-rows x 64 n-cols. grid (TOK/64, D/64).
// ---------------------------------------------------------------------------
__global__ __launch_bounds__(256) void k_out(
    const unsigned short* __restrict__ A,
    const unsigned short* __restrict__ Wt,
    const float* __restrict__ bo,
    float* __restrict__ C)
{
    const int tid  = threadIdx.x;
    const int lane = tid & 63, w = tid >> 6;
    const int g = lane >> 4, q = lane & 15;
    const int m0 = blockIdx.x * 64 + w * 16;
    const int n0 = blockIdx.y * 64;

    f32x4 c0 = {0.f, 0.f, 0.f, 0.f}, c1 = c0, c2 = c0, c3 = c0;
    #pragma unroll 4
    for (int kk = 0; kk < D_; kk += 32) {
        bf16x8 af  = *reinterpret_cast<const bf16x8*>(&A [(size_t)(m0 + q) * D_ + kk + 8 * g]);
        bf16x8 bf0 = *reinterpret_cast<const bf16x8*>(&Wt[(size_t)(n0 + q) * D_ + kk + 8 * g]);
        bf16x8 bf1 = *reinterpret_cast<const bf16x8*>(&Wt[(size_t)(n0 + 16 + q) * D_ + kk + 8 * g]);
        bf16x8 bf2 = *reinterpret_cast<const bf16x8*>(&Wt[(size_t)(n0 + 32 + q) * D_ + kk + 8 * g]);
        bf16x8 bf3 = *reinterpret_cast<const bf16x8*>(&Wt[(size_t)(n0 + 48 + q) * D_ + kk + 8 * g]);
        c0 = mfma16(af, bf0, c0);
        c1 = mfma16(af, bf1, c1);
        c2 = mfma16(af, bf2, c2);
        c3 = mfma16(af, bf3, c3);
    }
    float bia0 = bo[n0 + q],      bia1 = bo[n0 + 16 + q];
    float bia2 = bo[n0 + 32 + q], bia3 = bo[n0 + 48 + q];
    #pragma unroll
    for (int j = 0; j < 4; ++j) {
        size_t r = (size_t)(m0 + 4 * g + j) * D_;
        C[r + n0 + q]      = c0[j] + bia0;
        C[r + n0 + 16 + q] = c1[j] + bia1;
        C[r + n0 + 32 + q] = c2[j] + bia2;
        C[r + n0 + 48 + q] = c3[j] + bia3;
    }
}

// ---------------------------------------------------------------------------
extern "C" void kernel_launch(void* const* d_in, const int* in_sizes, int n_in,
                              void* d_out, int out_size, void* d_ws, size_t ws_size,
                              hipStream_t stream)
{
    const float* X  = (const float*)d_in[0];
    const float* Wq = (const float*)d_in[1];
    const float* bq = (const float*)d_in[2];
    const float* Wk = (const float*)d_in[3];
    const float* bk = (const float*)d_in[4];
    const float* Wv = (const float*)d_in[5];
    const float* bv = (const float*)d_in[6];
    const float* Wo = (const float*)d_in[7];
    const float* bo = (const float*)d_in[8];
    float* out = (float*)d_out;

    unsigned short* ws = (unsigned short*)d_ws;
    const size_t QN = (size_t)B_ * H_ * S_ * HD_;   // 4M elements
    unsigned short* Qb  = ws;             // 8 MB
    unsigned short* Kb  = ws + QN;        // 8 MB
    unsigned short* Vtb = ws + 2 * QN;    // 8 MB (transposed V)
    unsigned short* Ob  = ws + 3 * QN;    // 8 MB (attention output, bf16)
    unsigned short* WoT = ws + 4 * QN;    // 2 MB (Wo^T bf16)

    k_transpose_wo<<<dim3(16, 16), 256, 0, stream>>>(Wo, WoT);
    k_qkv<<<dim3(TOK / 64, H_, 3), 256, 0, stream>>>(X, Wq, bq, Wk, bk, Wv, bv, Qb, Kb, Vtb);
    k_attn<<<dim3(S_ / 64, B_ * H_), 256, 0, stream>>>(Qb, Kb, Vtb, Ob);
    k_out<<<dim3(TOK / 64, D_ / 64), 256, 0, stream>>>(Ob, WoT, bo, out);
}

// Round 4
// 180.904 us; speedup vs baseline: 1.5431x; 1.3915x over previous
//
#include <hip/hip_runtime.h>
#include <stdint.h>

#define B_  2
#define S_  2048
#define D_  1024
#define H_  16
#define HD_ 64
#define TOK (B_*S_)   // 4096

typedef __bf16 bf16x8 __attribute__((ext_vector_type(8)));
typedef __bf16 bf16x4 __attribute__((ext_vector_type(4)));
typedef float  f32x4  __attribute__((ext_vector_type(4)));

static_assert(sizeof(bf16x8) == 16, "bf16x8 must be 16B");
static_assert(sizeof(bf16x4) == 8,  "bf16x4 must be 8B");

__device__ __forceinline__ float fexp2(float x) { return __builtin_amdgcn_exp2f(x); }

__device__ __forceinline__ f32x4 mfma16(bf16x8 a, bf16x8 b, f32x4 c) {
    return __builtin_amdgcn_mfma_f32_16x16x32_bf16(a, b, c, 0, 0, 0);
}

// ---------------------------------------------------------------------------
// K0: Wo [1024(in)][1024(out)] fp32  ->  WoT [out][in] bf16
// grid (16,16), block 256
// ---------------------------------------------------------------------------
__global__ __launch_bounds__(256) void k_transpose_wo(
    const float* __restrict__ Wo, unsigned short* __restrict__ WoT)
{
    __shared__ float t[64][65];
    const int i0 = blockIdx.x * 64;   // in-dim tile
    const int o0 = blockIdx.y * 64;   // out-dim tile
    const int tid = threadIdx.x;
    #pragma unroll
    for (int p = 0; p < 16; ++p) {
        int idx = tid + p * 256;
        int r = idx >> 6, c = idx & 63;
        t[r][c] = Wo[(size_t)(i0 + r) * D_ + o0 + c];
    }
    __syncthreads();
    #pragma unroll
    for (int p = 0; p < 16; ++p) {
        int idx = tid + p * 256;
        int r = idx >> 6, c = idx & 63;   // r: out-row in tile, c: in-col in tile
        reinterpret_cast<__bf16*>(WoT)[(size_t)(o0 + r) * D_ + i0 + c] = (__bf16)t[c][r];
    }
}

// ---------------------------------------------------------------------------
// K1 (v2): per-head QKV projection via MFMA.
//  - X tile (128 tok x 64) fp32 -> bf16, XOR-swizzled LDS [128][64].
//  - W (64x64) staged fp32 [64][65], transposed in-block -> WT[e][d] bf16 LDS.
//  - 4 waves x 32 tokens; per wave 16 MFMAs (2 am x 4 bn x 2 ksub).
//   Q -> [B,H,S,HD] bf16 scaled by log2(e)/8;  K -> [B,H,S,HD] bf16;
//   V -> transposed [B,H,HD,S] bf16.
// grid (TOK/128, H, 3), block 256.
// ---------------------------------------------------------------------------
__global__ __launch_bounds__(256) void k_qkv(
    const float* __restrict__ X,
    const float* __restrict__ Wq, const float* __restrict__ bq,
    const float* __restrict__ Wk, const float* __restrict__ bk,
    const float* __restrict__ Wv, const float* __restrict__ bv,
    unsigned short* __restrict__ Qo, unsigned short* __restrict__ Ko,
    unsigned short* __restrict__ Vt)
{
    __shared__ float          Wf[64][65];       // fp32 W, padded (transpose source)
    __shared__ unsigned short Xl[128 * 64];     // bf16 X tile, swizzled slots
    __shared__ unsigned short Wl[64 * 64];      // bf16 W^T [e][d], swizzled slots

    const int tid  = threadIdx.x;
    const int lane = tid & 63, w = tid >> 6;
    const int g = lane >> 4, q = lane & 15;
    const int tok0 = blockIdx.x * 128;
    const int h    = blockIdx.y;
    const int z    = blockIdx.z;                  // 0=Q 1=K 2=V
    const float* W  = (z == 0) ? Wq : (z == 1) ? Wk : Wv;
    const float* bb = (z == 0) ? bq : (z == 1) ? bk : bv;

    // ---- stage W fp32 into padded LDS (4096 elts, 4 x float4 per thread) ----
    #pragma unroll
    for (int i = 0; i < 4; ++i) {
        int c = tid + 256 * i;
        int r = c >> 4, c4 = (c & 15) * 4;
        *reinterpret_cast<float4*>(&Wf[r][c4]) =
            *reinterpret_cast<const float4*>(&W[h * 4096 + r * 64 + c4]);
    }
    // ---- stage X: fp32 read, cvt bf16, swizzled write (8-elt chunks) ----
    #pragma unroll
    for (int i = 0; i < 4; ++i) {
        int c = tid + 256 * i;
        int row = c >> 3, slot = c & 7;
        const float* src = &X[(size_t)(tok0 + row) * D_ + h * HD_ + slot * 8];
        float4 x0 = *reinterpret_cast<const float4*>(src);
        float4 x1 = *reinterpret_cast<const float4*>(src + 4);
        bf16x8 v = { (__bf16)x0.x, (__bf16)x0.y, (__bf16)x0.z, (__bf16)x0.w,
                     (__bf16)x1.x, (__bf16)x1.y, (__bf16)x1.z, (__bf16)x1.w };
        *reinterpret_cast<bf16x8*>(
            reinterpret_cast<char*>(Xl) + row * 128 + ((slot ^ (row & 7)) * 16)) = v;
    }
    __syncthreads();

    // ---- transpose W -> Wl bf16 [e][d], swizzled (8-elt chunks) ----
    #pragma unroll
    for (int i = 0; i < 2; ++i) {
        int c = tid + 256 * i;
        int e = c >> 3, slot = c & 7;
        bf16x8 v;
        #pragma unroll
        for (int j = 0; j < 8; ++j) v[j] = (__bf16)Wf[slot * 8 + j][e];
        *reinterpret_cast<bf16x8*>(
            reinterpret_cast<char*>(Wl) + e * 128 + ((slot ^ (e & 7)) * 16)) = v;
    }
    __syncthreads();

    // ---- compute: wave w owns tokens [w*32, w*32+32) ----
    f32x4 acc[2][4] = {};
    #pragma unroll
    for (int s = 0; s < 2; ++s) {
        bf16x8 af[2], bfr[4];
        #pragma unroll
        for (int am = 0; am < 2; ++am) {
            int row  = w * 32 + am * 16 + q;
            int slot = (s * 4 + g) ^ (row & 7);
            af[am] = *reinterpret_cast<const bf16x8*>(
                reinterpret_cast<const char*>(Xl) + row * 128 + slot * 16);
        }
        #pragma unroll
        for (int bn = 0; bn < 4; ++bn) {
            int row  = bn * 16 + q;
            int slot = (s * 4 + g) ^ (row & 7);
            bfr[bn] = *reinterpret_cast<const bf16x8*>(
                reinterpret_cast<const char*>(Wl) + row * 128 + slot * 16);
        }
        #pragma unroll
        for (int am = 0; am < 2; ++am)
            #pragma unroll
            for (int bn = 0; bn < 4; ++bn)
                acc[am][bn] = mfma16(af[am], bfr[bn], acc[am][bn]);
    }

    // ---- epilogue ----
    const float scq = 0.18033688011112042f;  // log2(e)/8
    const int b  = tok0 >> 11;               // 128 | 2048 so block is within one b
    const int sb = (tok0 & (S_ - 1)) + w * 32;
    #pragma unroll
    for (int bn = 0; bn < 4; ++bn) {
        int e = bn * 16 + q;
        float bia = bb[h * HD_ + e];
        #pragma unroll
        for (int am = 0; am < 2; ++am) {
            int s4 = sb + am * 16 + 4 * g;
            if (z == 2) {
                bf16x4 ov = { (__bf16)(acc[am][bn][0] + bia), (__bf16)(acc[am][bn][1] + bia),
                              (__bf16)(acc[am][bn][2] + bia), (__bf16)(acc[am][bn][3] + bia) };
                *reinterpret_cast<bf16x4*>(
                    &Vt[((size_t)(b * H_ + h) * HD_ + e) * S_ + s4]) = ov;
            } else {
                float sc = (z == 0) ? scq : 1.0f;
                unsigned short* dst = (z == 0) ? Qo : Ko;
                __bf16* d16 = reinterpret_cast<__bf16*>(dst);
                #pragma unroll
                for (int j = 0; j < 4; ++j)
                    d16[((size_t)(b * H_ + h) * S_ + s4 + j) * HD_ + e] =
                        (__bf16)((acc[am][bn][j] + bia) * sc);
            }
        }
    }
}

// ---------------------------------------------------------------------------
// K2: flash attention (unchanged from round 3 — passing, 76.7 us).
// ---------------------------------------------------------------------------
__global__ __launch_bounds__(256) void k_attn(
    const unsigned short* __restrict__ Q,
    const unsigned short* __restrict__ K,
    const unsigned short* __restrict__ V,
    unsigned short* __restrict__ O)
{
    __shared__ unsigned short K_lds[2][32 * 72];
    __shared__ unsigned short V_lds[2][64 * 40];
    __shared__ unsigned short P_lds[4][16 * 40];

    const int bh = blockIdx.y;
    const unsigned short* Qp = Q + (size_t)bh * S_ * HD_;
    const unsigned short* Kp = K + (size_t)bh * S_ * HD_;
    const unsigned short* Vp = V + (size_t)bh * HD_ * S_;

    const int tid  = threadIdx.x;
    const int lane = tid & 63, w = tid >> 6;
    const int g = lane >> 4, q = lane & 15;
    const int q0 = blockIdx.x * 64 + w * 16;

    bf16x8 qf0 = *reinterpret_cast<const bf16x8*>(&Qp[(size_t)(q0 + q) * HD_ + 8 * g]);
    bf16x8 qf1 = *reinterpret_cast<const bf16x8*>(&Qp[(size_t)(q0 + q) * HD_ + 32 + 8 * g]);

    f32x4 acc0 = {0.f, 0.f, 0.f, 0.f}, acc1 = acc0, acc2 = acc0, acc3 = acc0;
    float m = -3.0e38f, lp = 0.0f;

    const int kr = tid >> 3, ks = (tid & 7) * 8;
    const int vr = tid >> 2, vs = (tid & 3) * 8;
    unsigned short* Pw = P_lds[w];

    const unsigned short* kSrc = Kp + (size_t)kr * HD_ + ks;
    const unsigned short* vSrc = Vp + (size_t)vr * S_  + vs;

    {
        uint4 k0 = *reinterpret_cast<const uint4*>(kSrc);
        uint4 v0 = *reinterpret_cast<const uint4*>(vSrc);
        *reinterpret_cast<uint4*>(&K_lds[0][kr * 72 + ks]) = k0;
        *reinterpret_cast<uint4*>(&V_lds[0][vr * 40 + vs]) = v0;
    }
    __syncthreads();

    const int NT = S_ / 32;
    for (int t = 0; t < NT; ++t) {
        const int cur = t & 1, nxt = cur ^ 1;

        uint4 kn, vn;
        const bool more = (t + 1 < NT);
        if (more) {
            kn = *reinterpret_cast<const uint4*>(kSrc + (size_t)(t + 1) * 32 * HD_);
            vn = *reinterpret_cast<const uint4*>(vSrc + (size_t)(t + 1) * 32);
        }

        const unsigned short* Kb = K_lds[cur];
        const unsigned short* Vb = V_lds[cur];
        bf16x8 k00 = *reinterpret_cast<const bf16x8*>(&Kb[q * 72 + 8 * g]);
        bf16x8 k01 = *reinterpret_cast<const bf16x8*>(&Kb[q * 72 + 32 + 8 * g]);
        bf16x8 k10 = *reinterpret_cast<const bf16x8*>(&Kb[(16 + q) * 72 + 8 * g]);
        bf16x8 k11 = *reinterpret_cast<const bf16x8*>(&Kb[(16 + q) * 72 + 32 + 8 * g]);
        bf16x8 vf0 = *reinterpret_cast<const bf16x8*>(&Vb[(0 * 16 + q) * 40 + 8 * g]);
        bf16x8 vf1 = *reinterpret_cast<const bf16x8*>(&Vb[(1 * 16 + q) * 40 + 8 * g]);
        bf16x8 vf2 = *reinterpret_cast<const bf16x8*>(&Vb[(2 * 16 + q) * 40 + 8 * g]);
        bf16x8 vf3 = *reinterpret_cast<const bf16x8*>(&Vb[(3 * 16 + q) * 40 + 8 * g]);

        f32x4 z4 = {0.f, 0.f, 0.f, 0.f};
        f32x4 s0 = mfma16(k00, qf0, z4); s0 = mfma16(k01, qf1, s0);
        f32x4 s1 = mfma16(k10, qf0, z4); s1 = mfma16(k11, qf1, s1);

        float pmax = fmaxf(fmaxf(fmaxf(s0[0], s0[1]), fmaxf(s0[2], s0[3])),
                           fmaxf(fmaxf(s1[0], s1[1]), fmaxf(s1[2], s1[3])));
        if (!__all(pmax - m <= 8.0f)) {
            float pm = pmax;
            pm = fmaxf(pm, __shfl_xor(pm, 16));
            pm = fmaxf(pm, __shfl_xor(pm, 32));
            float mn  = fmaxf(m, pm);
            float scl = fexp2(m - mn);
            m = mn;
            lp *= scl;
            acc0 *= scl; acc1 *= scl; acc2 *= scl; acc3 *= scl;
        }
        float p0 = fexp2(s0[0] - m), p1 = fexp2(s0[1] - m);
        float p2 = fexp2(s0[2] - m), p3 = fexp2(s0[3] - m);
        float p4 = fexp2(s1[0] - m), p5 = fexp2(s1[1] - m);
        float p6 = fexp2(s1[2] - m), p7 = fexp2(s1[3] - m);
        lp += ((p0 + p1) + (p2 + p3)) + ((p4 + p5) + (p6 + p7));

        bf16x4 pa = { (__bf16)p0, (__bf16)p1, (__bf16)p2, (__bf16)p3 };
        bf16x4 pb = { (__bf16)p4, (__bf16)p5, (__bf16)p6, (__bf16)p7 };
        *reinterpret_cast<bf16x4*>(&Pw[q * 40 + 4 * g])      = pa;
        *reinterpret_cast<bf16x4*>(&Pw[q * 40 + 16 + 4 * g]) = pb;

        bf16x8 pf = *reinterpret_cast<const bf16x8*>(&Pw[q * 40 + 8 * g]);
        acc0 = mfma16(vf0, pf, acc0);
        acc1 = mfma16(vf1, pf, acc1);
        acc2 = mfma16(vf2, pf, acc2);
        acc3 = mfma16(vf3, pf, acc3);

        if (more) {
            *reinterpret_cast<uint4*>(&K_lds[nxt][kr * 72 + ks]) = kn;
            *reinterpret_cast<uint4*>(&V_lds[nxt][vr * 40 + vs]) = vn;
        }
        __syncthreads();
    }

    lp += __shfl_xor(lp, 16);
    lp += __shfl_xor(lp, 32);
    const float inv = 1.0f / lp;
    const int b = bh >> 4, h = bh & 15;
    size_t row = (size_t)(b * S_ + q0 + q) * D_ + h * HD_ + 4 * g;
    __bf16* Ob = reinterpret_cast<__bf16*>(O);
    bf16x4 o0 = { (__bf16)(acc0[0]*inv), (__bf16)(acc0[1]*inv),
                  (__bf16)(acc0[2]*inv), (__bf16)(acc0[3]*inv) };
    bf16x4 o1 = { (__bf16)(acc1[0]*inv), (__bf16)(acc1[1]*inv),
                  (__bf16)(acc1[2]*inv), (__bf16)(acc1[3]*inv) };
    bf16x4 o2 = { (__bf16)(acc2[0]*inv), (__bf16)(acc2[1]*inv),
                  (__bf16)(acc2[2]*inv), (__bf16)(acc2[3]*inv) };
    bf16x4 o3 = { (__bf16)(acc3[0]*inv), (__bf16)(acc3[1]*inv),
                  (__bf16)(acc3[2]*inv), (__bf16)(acc3[3]*inv) };
    *reinterpret_cast<bf16x4*>(&Ob[row + 0])  = o0;
    *reinterpret_cast<bf16x4*>(&Ob[row + 16]) = o1;
    *reinterpret_cast<bf16x4*>(&Ob[row + 32]) = o2;
    *reinterpret_cast<bf16x4*>(&Ob[row + 48]) = o3;
}

// ---------------------------------------------------------------------------
// K3 (v2): out = O_attn(bf16) @ Wo^T_rows + bo, fp32 out.
// 2-phase LDS GEMM: 128x128 tile, BK=64, double-buffered swizzled LDS,
// reg-staged async-split (T14). 4 waves, each a 64x64 quadrant.
// grid (TOK/128=32, D/128=8), block 256.
// ---------------------------------------------------------------------------
__global__ __launch_bounds__(256) void k_out(
    const unsigned short* __restrict__ A,
    const unsigned short* __restrict__ Wt,
    const float* __restrict__ bo,
    float* __restrict__ C)
{
    __shared__ unsigned short Al[2][128 * 64];   // rows=m, 128B rows, swizzled slots
    __shared__ unsigned short Bl[2][128 * 64];   // rows=n (Wt rows), same layout

    const int tid  = threadIdx.x;
    const int lane = tid & 63, w = tid >> 6;
    const int g = lane >> 4, q = lane & 15;
    const int wr = w & 1, wc = w >> 1;
    const int m0 = blockIdx.x * 128;
    const int n0 = blockIdx.y * 128;

    // staging map: chunk c = tid + 256*i : row = c>>3, slot = c&7
    int    sbyte[4];
    size_t sgA[4], sgB[4];
    #pragma unroll
    for (int i = 0; i < 4; ++i) {
        int c = tid + 256 * i;
        int row = c >> 3, slot = c & 7;
        sbyte[i] = row * 128 + ((slot ^ (row & 7)) * 16);
        sgA[i] = (size_t)(m0 + row) * D_ + slot * 8;
        sgB[i] = (size_t)(n0 + row) * D_ + slot * 8;
    }

    uint4 ra[4], rb[4];
    #pragma unroll
    for (int i = 0; i < 4; ++i) {
        ra[i] = *reinterpret_cast<const uint4*>(A  + sgA[i]);
        rb[i] = *reinterpret_cast<const uint4*>(Wt + sgB[i]);
    }
    #pragma unroll
    for (int i = 0; i < 4; ++i) {
        *reinterpret_cast<uint4*>(reinterpret_cast<char*>(Al[0]) + sbyte[i]) = ra[i];
        *reinterpret_cast<uint4*>(reinterpret_cast<char*>(Bl[0]) + sbyte[i]) = rb[i];
    }
    __syncthreads();

    f32x4 acc[4][4] = {};
    const int NKT = D_ / 64;   // 16
    for (int kt = 0; kt < NKT; ++kt) {
        const int cur = kt & 1, nxt = cur ^ 1;
        const bool more = (kt + 1 < NKT);
        if (more) {
            #pragma unroll
            for (int i = 0; i < 4; ++i) {
                ra[i] = *reinterpret_cast<const uint4*>(A  + sgA[i] + (kt + 1) * 64);
                rb[i] = *reinterpret_cast<const uint4*>(Wt + sgB[i] + (kt + 1) * 64);
            }
        }
        const char* Ab = reinterpret_cast<const char*>(Al[cur]);
        const char* Bb = reinterpret_cast<const char*>(Bl[cur]);
        #pragma unroll
        for (int s = 0; s < 2; ++s) {
            bf16x8 af[4], bfr[4];
            #pragma unroll
            for (int am = 0; am < 4; ++am) {
                int row  = wr * 64 + am * 16 + q;
                int slot = (s * 4 + g) ^ (row & 7);
                af[am] = *reinterpret_cast<const bf16x8*>(Ab + row * 128 + slot * 16);
            }
            #pragma unroll
            for (int bn = 0; bn < 4; ++bn) {
                int row  = wc * 64 + bn * 16 + q;
                int slot = (s * 4 + g) ^ (row & 7);
                bfr[bn] = *reinterpret_cast<const bf16x8*>(Bb + row * 128 + slot * 16);
            }
            #pragma unroll
            for (int am = 0; am < 4; ++am)
                #pragma unroll
                for (int bn = 0; bn < 4; ++bn)
                    acc[am][bn] = mfma16(af[am], bfr[bn], acc[am][bn]);
        }
        if (more) {
            #pragma unroll
            for (int i = 0; i < 4; ++i) {
                *reinterpret_cast<uint4*>(reinterpret_cast<char*>(Al[nxt]) + sbyte[i]) = ra[i];
                *reinterpret_cast<uint4*>(reinterpret_cast<char*>(Bl[nxt]) + sbyte[i]) = rb[i];
            }
        }
        __syncthreads();
    }

    // epilogue: C = acc + bias
    #pragma unroll
    for (int bn = 0; bn < 4; ++bn) {
        int n = n0 + wc * 64 + bn * 16 + q;
        float bia = bo[n];
        #pragma unroll
        for (int am = 0; am < 4; ++am) {
            int mbase = m0 + wr * 64 + am * 16 + 4 * g;
            #pragma unroll
            for (int j = 0; j < 4; ++j)
                C[(size_t)(mbase + j) * D_ + n] = acc[am][bn][j] + bia;
        }
    }
}

// ---------------------------------------------------------------------------
extern "C" void kernel_launch(void* const* d_in, const int* in_sizes, int n_in,
                              void* d_out, int out_size, void* d_ws, size_t ws_size,
                              hipStream_t stream)
{
    const float* X  = (const float*)d_in[0];
    const float* Wq = (const float*)d_in[1];
    const float* bq = (const float*)d_in[2];
    const float* Wk = (const float*)d_in[3];
    const float* bk = (const float*)d_in[4];
    const float* Wv = (const float*)d_in[5];
    const float* bv = (const float*)d_in[6];
    const float* Wo = (const float*)d_in[7];
    const float* bo = (const float*)d_in[8];
    float* out = (float*)d_out;

    unsigned short* ws = (unsigned short*)d_ws;
    const size_t QN = (size_t)B_ * H_ * S_ * HD_;   // 4M elements
    unsigned short* Qb  = ws;             // 8 MB
    unsigned short* Kb  = ws + QN;        // 8 MB
    unsigned short* Vtb = ws + 2 * QN;    // 8 MB (transposed V)
    unsigned short* Ob  = ws + 3 * QN;    // 8 MB (attention output, bf16)
    unsigned short* WoT = ws + 4 * QN;    // 2 MB (Wo^T bf16)

    k_transpose_wo<<<dim3(16, 16), 256, 0, stream>>>(Wo, WoT);
    k_qkv<<<dim3(TOK / 128, H_, 3), 256, 0, stream>>>(X, Wq, bq, Wk, bk, Wv, bv, Qb, Kb, Vtb);
    k_attn<<<dim3(S_ / 64, B_ * H_), 256, 0, stream>>>(Qb, Kb, Vtb, Ob);
    k_out<<<dim3(TOK / 128, D_ / 128), 256, 0, stream>>>(Ob, WoT, bo, out);
}